// Round 8
// baseline (225.022 us; speedup 1.0000x reference)
//
#include <hip/hip_runtime.h>
#include <math.h>

#define Bdim  2
#define Nseq  2048
#define Dmod  512
#define Hn    8
#define DHd   64
#define HID   2730
#define HHALF 1365
#define HC    1408      // combined hidden, padded (22*64)
#define NPACK 2816      // packed fc1 output cols (2*HC)
#define ROWS  4096      // Bdim*Nseq
#define NSPLIT 4        // attention split-K (runtime loop bound keeps VGPR low)

typedef __bf16 bf16x8 __attribute__((ext_vector_type(8)));
typedef __bf16 bf16x4 __attribute__((ext_vector_type(4)));
typedef float  f32x4  __attribute__((ext_vector_type(4)));

__device__ __forceinline__ void glds16(const __bf16* g, __bf16* l) {
    __builtin_amdgcn_global_load_lds(
        (const __attribute__((address_space(1))) void*)g,
        (__attribute__((address_space(3))) void*)l, 16, 0, 0);
}

// ---------------- LN body (shared) ----------------
__device__ __forceinline__ void ln_body(
    int row, int tid, const float* __restrict__ x, const float* __restrict__ w,
    const float* __restrict__ b, __bf16* __restrict__ out)
{
    const float* xr = x + (size_t)row * Dmod;
    float2 v = *(const float2*)(xr + tid * 2);
    float s  = v.x + v.y;
    float sq = v.x * v.x + v.y * v.y;
#pragma unroll
    for (int m = 1; m < 64; m <<= 1) {
        s  += __shfl_xor(s, m, 64);
        sq += __shfl_xor(sq, m, 64);
    }
    __shared__ float ss[4], ssq[4];
    const int wv = tid >> 6;
    if ((tid & 63) == 0) { ss[wv] = s; ssq[wv] = sq; }
    __syncthreads();
    s  = ss[0] + ss[1] + ss[2] + ss[3];
    sq = ssq[0] + ssq[1] + ssq[2] + ssq[3];
    const float mean = s * (1.0f / Dmod);
    const float var  = sq * (1.0f / Dmod) - mean * mean;
    const float rstd = rsqrtf(var + 1e-5f);
    float2 wv2 = *(const float2*)(w + tid * 2);
    float2 bv2 = *(const float2*)(b + tid * 2);
    __bf16* orow = out + (size_t)row * Dmod + tid * 2;
    orow[0] = (__bf16)((v.x - mean) * rstd * wv2.x + bv2.x);
    orow[1] = (__bf16)((v.y - mean) * rstd * wv2.y + bv2.y);
}

// ---------------- fused weight conversion + LN1 ----------------
#define SEG0 (1536*512)
#define SEG1 (512*512)
#define SEG2 (NPACK*512)
#define SEG3 (512*HC)
#define CONV_BLOCKS ((SEG0 + SEG1 + SEG2 + SEG3) / 256)
__global__ __launch_bounds__(256) void convert_ln(
    const float* __restrict__ q_w, const float* __restrict__ k_w,
    const float* __restrict__ v_w, const float* __restrict__ o_w,
    const float* __restrict__ fc1_w, const float* __restrict__ fc2_w,
    __bf16* __restrict__ wqkv, __bf16* __restrict__ wo,
    __bf16* __restrict__ wfc1p, __bf16* __restrict__ wfc2p,
    const float* __restrict__ x, const float* __restrict__ ln1w,
    const float* __restrict__ ln1b, __bf16* __restrict__ xn)
{
    if (blockIdx.x >= CONV_BLOCKS) {
        ln_body(blockIdx.x - CONV_BLOCKS, threadIdx.x, x, ln1w, ln1b, xn);
        return;
    }
    int idx = blockIdx.x * 256 + threadIdx.x;
    if (idx < SEG0) {
        int n = idx >> 9, k = idx & 511;
        float v = (n < 512) ? q_w[n * 512 + k]
                : (n < 1024) ? k_w[(n - 512) * 512 + k]
                : v_w[(n - 1024) * 512 + k];
        wqkv[idx] = (__bf16)v;
        return;
    }
    idx -= SEG0;
    if (idx < SEG1) { wo[idx] = (__bf16)o_w[idx]; return; }
    idx -= SEG1;
    if (idx < SEG2) {
        int n = idx >> 9, k = idx & 511;
        int j = n >> 5, u = n & 31;
        int base = j * 16 + (u & 15);
        float v = 0.0f;
        if (base < HHALF) {
            int hidx = base + ((u & 16) ? HHALF : 0);
            v = fc1_w[(size_t)hidx * 512 + k];
        }
        wfc1p[idx] = (__bf16)v;
        return;
    }
    idx -= SEG2;
    if (idx < SEG3) {
        int n = idx / HC, k = idx - n * HC;
        float v = (k < HHALF) ? fc2_w[(size_t)n * HHALF + k] : 0.0f;
        wfc2p[idx] = (__bf16)v;
    }
}

// ---------------- LN2 ----------------
__global__ __launch_bounds__(256) void ln_kernel(
    const float* __restrict__ x, const float* __restrict__ w,
    const float* __restrict__ b, __bf16* __restrict__ out)
{
    ln_body(blockIdx.x, threadIdx.x, x, w, b, out);
}

// ---------------- 64x64 residual GEMM, BK=64, XOR-swizzled glds16 ----------------
// out_f32 = res + g*(A·B^T + bias). K % 64 == 0.
__global__ __launch_bounds__(256) void gemm_res(
    const __bf16* __restrict__ A, int lda,
    const __bf16* __restrict__ Bw, int ldb,
    const float* __restrict__ bias, int K,
    float* __restrict__ out_f32, int ld_out,
    const float* __restrict__ res, const float* __restrict__ g)
{
    __shared__ __bf16 smem[2 * 64 * 64];   // As | Bs, row stride 64 elems
    __bf16* As = smem;
    __bf16* Bs = smem + 64 * 64;
    const int tid  = threadIdx.x;
    const int wave = tid >> 6, lane = tid & 63;
    const int t    = lane & 15, quad = lane >> 4;
    const int m0   = blockIdx.x * 64;
    const int n0   = blockIdx.y * 64;

    // staging chunks c = tid, tid+256: row = c>>3, pos = c&7, gchunk = pos ^ (row&7)
    const int r0 = tid >> 3,           p0 = tid & 7;
    const int r1 = (tid + 256) >> 3,   p1 = tid & 7;
    const int g0 = (p0 ^ (r0 & 7)) * 8;
    const int g1 = (p1 ^ (r1 & 7)) * 8;
    const __bf16* a0p = A  + (size_t)(m0 + r0) * lda + g0;
    const __bf16* a1p = A  + (size_t)(m0 + r1) * lda + g1;
    const __bf16* b0p = Bw + (size_t)(n0 + r0) * ldb + g0;
    const __bf16* b1p = Bw + (size_t)(n0 + r1) * ldb + g1;

    // fragment offsets: row*64 + ((half*4+quad) ^ (t&7))*8
    const int sw = t & 7;
    f32x4 acc[4] = {};

    for (int k0 = 0; k0 < K; k0 += 64) {
        __syncthreads();
        glds16(a0p + k0, As + tid * 8);
        glds16(a1p + k0, As + (tid + 256) * 8);
        glds16(b0p + k0, Bs + tid * 8);
        glds16(b1p + k0, Bs + (tid + 256) * 8);
        __syncthreads();
#pragma unroll
        for (int half = 0; half < 2; ++half) {
            const int co = ((half * 4 + quad) ^ sw) * 8;
            bf16x8 a = *(const bf16x8*)(As + (wave * 16 + t) * 64 + co);
#pragma unroll
            for (int ct = 0; ct < 4; ++ct) {
                bf16x8 b = *(const bf16x8*)(Bs + (ct * 16 + t) * 64 + co);
                acc[ct] = __builtin_amdgcn_mfma_f32_16x16x32_bf16(a, b, acc[ct], 0, 0, 0);
            }
        }
    }

    const int row_base = m0 + wave * 16 + quad * 4;
#pragma unroll
    for (int ct = 0; ct < 4; ++ct) {
        const int col = n0 + ct * 16 + t;
        const float bb = bias[col];
#pragma unroll
        for (int r = 0; r < 4; ++r) {
            const int row = row_base + r;
            out_f32[(size_t)row * ld_out + col] =
                res[(size_t)row * ld_out + col] + g[col] * (acc[ct][r] + bb);
        }
    }
}

// ---------------- 128x128 GEMM core, BK=64, XOR-swizzled glds16 ----------------
// Stages A[128][64], B[128][64] per iter; 32 MFMA per wave per iter.
#define QKV_KLOOP(A_, W_, KTOT)                                                   \
    for (int k0 = 0; k0 < (KTOT); k0 += 64) {                                     \
        __syncthreads();                                                          \
        glds16(A_ + (size_t)(m0 + ar0) * Dmod + k0 + ag0, As + tid * 8);          \
        glds16(A_ + (size_t)(m0 + ar1) * Dmod + k0 + ag1, As + (tid + 256) * 8);  \
        glds16(A_ + (size_t)(m0 + ar2) * Dmod + k0 + ag2, As + (tid + 512) * 8);  \
        glds16(A_ + (size_t)(m0 + ar3) * Dmod + k0 + ag3, As + (tid + 768) * 8);  \
        glds16(W_ + (size_t)(n0 + ar0) * Dmod + k0 + ag0, Bs + tid * 8);          \
        glds16(W_ + (size_t)(n0 + ar1) * Dmod + k0 + ag1, Bs + (tid + 256) * 8);  \
        glds16(W_ + (size_t)(n0 + ar2) * Dmod + k0 + ag2, Bs + (tid + 512) * 8);  \
        glds16(W_ + (size_t)(n0 + ar3) * Dmod + k0 + ag3, Bs + (tid + 768) * 8);  \
        __syncthreads();                                                          \
        _Pragma("unroll")                                                         \
        for (int half = 0; half < 2; ++half) {                                    \
            const int co = ((half * 4 + quad) ^ sw) * 8;                          \
            bf16x8 af[4], bfr[4];                                                 \
            _Pragma("unroll")                                                     \
            for (int mi = 0; mi < 4; ++mi)                                        \
                af[mi] = *(const bf16x8*)(As + (mr + mi * 16 + t) * 64 + co);     \
            _Pragma("unroll")                                                     \
            for (int ni = 0; ni < 4; ++ni)                                        \
                bfr[ni] = *(const bf16x8*)(Bs + (nr + ni * 16 + t) * 64 + co);    \
            _Pragma("unroll")                                                     \
            for (int mi = 0; mi < 4; ++mi)                                        \
                _Pragma("unroll")                                                 \
                for (int ni = 0; ni < 4; ++ni)                                    \
                    acc[mi][ni] = __builtin_amdgcn_mfma_f32_16x16x32_bf16(        \
                        af[mi], bfr[ni], acc[mi][ni], 0, 0, 0);                   \
        }                                                                         \
    }

#define GEMM128_SETUP                                                   \
    const int tid  = threadIdx.x;                                       \
    const int wave = tid >> 6, lane = tid & 63;                         \
    const int t    = lane & 15, quad = lane >> 4;                       \
    const int m0   = blockIdx.x * 128, n0 = blockIdx.y * 128;           \
    const int mr   = (wave & 1) * 64,  nr = (wave >> 1) * 64;           \
    const int ar0 = tid >> 3,          ag0 = ((tid & 7) ^ (ar0 & 7)) * 8;  \
    const int ar1 = (tid + 256) >> 3,  ag1 = ((tid & 7) ^ (ar1 & 7)) * 8;  \
    const int ar2 = (tid + 512) >> 3,  ag2 = ((tid & 7) ^ (ar2 & 7)) * 8;  \
    const int ar3 = (tid + 768) >> 3,  ag3 = ((tid & 7) ^ (ar3 & 7)) * 8;  \
    const int sw  = t & 7;

// ---------------- QKV GEMM (BK=64); V third written transposed via LDS ----------------
#define LDT 136
__global__ __launch_bounds__(256) void qkv_gemm128(
    const __bf16* __restrict__ A, const __bf16* __restrict__ W,
    const float* __restrict__ qb_, const float* __restrict__ kb_,
    const float* __restrict__ vb_,
    __bf16* __restrict__ qk, __bf16* __restrict__ vtg)
{
    __shared__ __bf16 smem[2 * 128 * 64];   // As | Bs; reused for V transpose
    __bf16* As = smem;
    __bf16* Bs = smem + 8192;
    GEMM128_SETUP
    f32x4 acc[4][4] = {};
    QKV_KLOOP(A, W, Dmod)

    const int y = blockIdx.y;
    if (y < 8) {
#pragma unroll
        for (int mi = 0; mi < 4; ++mi) {
            const int row_base = m0 + mr + mi * 16 + quad * 4;
#pragma unroll
            for (int ni = 0; ni < 4; ++ni) {
                const int col = n0 + nr + ni * 16 + t;
                const float bb = (col < 512) ? qb_[col] : kb_[col - 512];
#pragma unroll
                for (int r = 0; r < 4; ++r)
                    qk[(size_t)(row_base + r) * 1024 + col] = (__bf16)(acc[mi][ni][r] + bb);
            }
        }
    } else {
        // V: transpose via LDS, two 64-dh passes, b128 stores
        const int tok0 = m0 & 2047;
        const int bI   = m0 >> 11;
#pragma unroll
        for (int half = 0; half < 2; ++half) {
            __syncthreads();
            if ((wave >> 1) == half) {
#pragma unroll
                for (int ni = 0; ni < 4; ++ni) {
                    const int dh = ni * 16 + t;
                    const float bb = vb_[(y - 8) * 128 + half * 64 + dh];
#pragma unroll
                    for (int mi = 0; mi < 4; ++mi) {
                        const int n = mr + mi * 16 + quad * 4;
                        bf16x4 pk;
#pragma unroll
                        for (int r = 0; r < 4; ++r) pk[r] = (__bf16)(acc[mi][ni][r] + bb);
                        *(bf16x4*)(smem + dh * LDT + n) = pk;
                    }
                }
            }
            __syncthreads();
            const int hh = (y - 8) * 2 + half;
            const size_t rowbase = (size_t)(bI * 8 + hh) * 64;
#pragma unroll
            for (int j = 0; j < 4; ++j) {
                int chunk = tid + j * 256;
                int dr = chunk >> 4, cc = (chunk & 15) * 8;
                bf16x8 vv = *(const bf16x8*)(smem + dr * LDT + cc);
                *(bf16x8*)(vtg + (rowbase + dr) * Nseq + tok0 + cc) = vv;
            }
        }
    }
}

// ---------------- fc1 GEMM (BK=64) with fused SwiGLU epilogue ----------------
__global__ __launch_bounds__(256) void fc1_gemm128(
    const __bf16* __restrict__ A, const __bf16* __restrict__ W,
    const float* __restrict__ fc1_b_, __bf16* __restrict__ out)
{
    __shared__ __bf16 smem[2 * 128 * 64];
    __bf16* As = smem;
    __bf16* Bs = smem + 8192;
    GEMM128_SETUP
    f32x4 acc[4][4] = {};
    QKV_KLOOP(A, W, Dmod)

#pragma unroll
    for (int mi = 0; mi < 4; ++mi) {
        const int row_base = m0 + mr + mi * 16 + quad * 4;
#pragma unroll
        for (int gI = 0; gI < 2; ++gI) {
            const int base = n0 + nr + gI * 32;
            const int hb = (base >> 5) * 16 + t;
            const bool valid = hb < HHALF;
            const float b1 = valid ? fc1_b_[hb] : 0.0f;
            const float b2 = valid ? fc1_b_[HHALF + hb] : 0.0f;
#pragma unroll
            for (int r = 0; r < 4; ++r) {
                float a = acc[mi][2 * gI][r] + b1;
                float c = acc[mi][2 * gI + 1][r] + b2;
                float sw2 = a / (1.0f + __expf(-a)) * c;
                out[(size_t)(row_base + r) * HC + hb] = (__bf16)sw2;
            }
        }
    }
}

// ---------------- Flash attention, split-K (runtime bound), no-max softmax ----------------
// grid: (Nseq/64, Hn, Bdim*NSPLIT); z: s=z>>1, b=z&1; ktper passed at runtime
__global__ __launch_bounds__(256) void attn_kernel(
    const __bf16* __restrict__ qk, const __bf16* __restrict__ vt,
    const float* __restrict__ coords,
    __bf16* __restrict__ op, float* __restrict__ lp, int ktper)
{
    constexpr int LD = 72;
    __shared__ __bf16 Ks[64][LD];
    __shared__ __bf16 Vt[64][LD];
    __shared__ __bf16 Ps[64][LD];
    __shared__ float2 kco[64];

    const int qt = blockIdx.x, h = blockIdx.y;
    const int s = blockIdx.z >> 1, b = blockIdx.z & 1;
    const int bh = b * Hn + h;
    const int tid = threadIdx.x;
    const int wave = tid >> 6, lane = tid & 63;
    const int t = lane & 15, quad = lane >> 4;
    const float c1 = 0.125f * 1.44269504f;
    const float d1 = exp2f(-(float)(h + 1)) * 1.44269504f;

    const int qrow = qt * 64 + wave * 16 + t;
    const size_t qbase = (size_t)(b * Nseq + qrow) * 1024 + h * DHd;
    bf16x8 bq0 = *(const bf16x8*)(qk + qbase + quad * 8);
    bf16x8 bq1 = *(const bf16x8*)(qk + qbase + 32 + quad * 8);
    float2 qc = *(const float2*)(coords + (size_t)(b * Nseq + qrow) * 2);
    const float qx = qc.x, qy = qc.y;

    const int sr = tid >> 3, scc = (tid & 7) * 8;
    const __bf16* kbase = qk + (size_t)(b * Nseq) * 1024 + 512 + h * DHd;
    const __bf16* vbase = vt + (size_t)(bh * 64) * Nseq;

    bf16x8 kreg0, kreg1, vreg0, vreg1;
    float2 kcreg = {0.f, 0.f};
    int kn = s * ktper * 64;
    kreg0 = *(const bf16x8*)(kbase + (size_t)(kn + sr) * 1024 + scc);
    kreg1 = *(const bf16x8*)(kbase + (size_t)(kn + sr + 32) * 1024 + scc);
    vreg0 = *(const bf16x8*)(vbase + (size_t)sr * Nseq + kn + scc);
    vreg1 = *(const bf16x8*)(vbase + (size_t)(sr + 32) * Nseq + kn + scc);
    if (tid < 64) kcreg = *(const float2*)(coords + (size_t)(b * Nseq + kn + tid) * 2);

    f32x4 o[4] = {};
    float lrun = 0.0f;

    for (int it = 0; it < ktper; ++it) {
        __syncthreads();
        *(bf16x8*)(&Ks[sr][scc])      = kreg0;
        *(bf16x8*)(&Ks[sr + 32][scc]) = kreg1;
        *(bf16x8*)(&Vt[sr][scc])      = vreg0;
        *(bf16x8*)(&Vt[sr + 32][scc]) = vreg1;
        if (tid < 64) kco[tid] = kcreg;
        __syncthreads();
        if (it + 1 < ktper) {
            const int k2 = kn + 64;
            kreg0 = *(const bf16x8*)(kbase + (size_t)(k2 + sr) * 1024 + scc);
            kreg1 = *(const bf16x8*)(kbase + (size_t)(k2 + sr + 32) * 1024 + scc);
            vreg0 = *(const bf16x8*)(vbase + (size_t)sr * Nseq + k2 + scc);
            vreg1 = *(const bf16x8*)(vbase + (size_t)(sr + 32) * Nseq + k2 + scc);
            if (tid < 64) kcreg = *(const float2*)(coords + (size_t)(b * Nseq + k2 + tid) * 2);
        }

        f32x4 sA[4];
#pragma unroll
        for (int am = 0; am < 4; ++am) {
            bf16x8 a0 = *(const bf16x8*)(&Ks[am * 16 + t][quad * 8]);
            bf16x8 a1 = *(const bf16x8*)(&Ks[am * 16 + t][32 + quad * 8]);
            f32x4 z = {};
            z = __builtin_amdgcn_mfma_f32_16x16x32_bf16(a0, bq0, z, 0, 0, 0);
            sA[am] = __builtin_amdgcn_mfma_f32_16x16x32_bf16(a1, bq1, z, 0, 0, 0);
        }

        float p[4][4];
#pragma unroll
        for (int am = 0; am < 4; ++am)
#pragma unroll
            for (int r = 0; r < 4; ++r) {
                float2 kc = kco[am * 16 + quad * 4 + r];
                float dx = qx - kc.x, dy = qy - kc.y;
                float dist = __builtin_amdgcn_sqrtf(dx * dx + dy * dy);
                float e = __builtin_amdgcn_exp2f(sA[am][r] * c1 - d1 * dist);
                p[am][r] = e;
                lrun += e;
            }

#pragma unroll
        for (int am = 0; am < 4; ++am) {
            bf16x4 pk;
#pragma unroll
            for (int r = 0; r < 4; ++r) pk[r] = (__bf16)p[am][r];
            *(bf16x4*)(&Ps[wave * 16 + t][am * 16 + quad * 4]) = pk;
        }

        bf16x8 ap0 = *(const bf16x8*)(&Ps[wave * 16 + t][quad * 8]);
        bf16x8 ap1 = *(const bf16x8*)(&Ps[wave * 16 + t][32 + quad * 8]);
#pragma unroll
        for (int ct = 0; ct < 4; ++ct) {
            bf16x8 bv0 = *(const bf16x8*)(&Vt[ct * 16 + t][quad * 8]);
            bf16x8 bv1 = *(const bf16x8*)(&Vt[ct * 16 + t][32 + quad * 8]);
            o[ct] = __builtin_amdgcn_mfma_f32_16x16x32_bf16(ap0, bv0, o[ct], 0, 0, 0);
            o[ct] = __builtin_amdgcn_mfma_f32_16x16x32_bf16(ap1, bv1, o[ct], 0, 0, 0);
        }
        kn += 64;
    }

    lrun += __shfl_xor(lrun, 16, 64);
    lrun += __shfl_xor(lrun, 32, 64);
    if (quad == 0)
        lp[(((size_t)s * Bdim + b) * Hn + h) * Nseq + qt * 64 + wave * 16 + t] = lrun;

    const int orow_base = qt * 64 + wave * 16 + quad * 4;
#pragma unroll
    for (int ct = 0; ct < 4; ++ct)
#pragma unroll
        for (int r = 0; r < 4; ++r) {
            size_t row = (size_t)s * ROWS + b * Nseq + orow_base + r;
            op[row * Dmod + h * DHd + ct * 16 + t] = (__bf16)o[ct][r];
        }
}

// ---------------- merge split-K partials (bf16 in, bf16 out) ----------------
__global__ __launch_bounds__(256) void merge_kernel(
    const __bf16* __restrict__ op, const float* __restrict__ lp,
    __bf16* __restrict__ ctx)
{
    int idx = blockIdx.x * 256 + threadIdx.x;
    int row = idx >> 7, c4 = (idx & 127) * 4;
    int h = c4 >> 6;
    int b = row >> 11, n = row & 2047;
    float l = 0.0f;
#pragma unroll
    for (int s = 0; s < NSPLIT; ++s)
        l += lp[(((size_t)s * Bdim + b) * Hn + h) * Nseq + n];
    float rl = __builtin_amdgcn_rcpf(l);
    float oa[4] = {0.f, 0.f, 0.f, 0.f};
#pragma unroll
    for (int s = 0; s < NSPLIT; ++s) {
        bf16x4 ov = *(const bf16x4*)(op + ((size_t)s * ROWS + row) * Dmod + c4);
#pragma unroll
        for (int j = 0; j < 4; ++j) oa[j] += (float)ov[j];
    }
    bf16x4 r;
#pragma unroll
    for (int j = 0; j < 4; ++j) r[j] = (__bf16)(oa[j] * rl);
    *(bf16x4*)(ctx + (size_t)row * Dmod + c4) = r;
}

// ---------------- launch ----------------
extern "C" void kernel_launch(void* const* d_in, const int* in_sizes, int n_in,
                              void* d_out, int out_size, void* d_ws, size_t ws_size,
                              hipStream_t stream)
{
    (void)in_sizes; (void)n_in; (void)out_size; (void)ws_size;
    const float* x      = (const float*)d_in[0];
    const float* coords = (const float*)d_in[1];
    const float* q_w    = (const float*)d_in[2];
    const float* q_b    = (const float*)d_in[3];
    const float* k_w    = (const float*)d_in[4];
    const float* k_b    = (const float*)d_in[5];
    const float* v_w    = (const float*)d_in[6];
    const float* v_b    = (const float*)d_in[7];
    const float* o_w    = (const float*)d_in[8];
    const float* o_b    = (const float*)d_in[9];
    const float* gamma1 = (const float*)d_in[10];
    const float* ln1_w  = (const float*)d_in[11];
    const float* ln1_b  = (const float*)d_in[12];
    const float* fc1_w  = (const float*)d_in[13];
    const float* fc1_b  = (const float*)d_in[14];
    const float* fc2_w  = (const float*)d_in[15];
    const float* fc2_b  = (const float*)d_in[16];
    const float* gamma2 = (const float*)d_in[17];
    const float* ln2_w  = (const float*)d_in[18];
    const float* ln2_b  = (const float*)d_in[19];

    size_t off = 0;
    auto alloc = [&](size_t bytes) {
        void* p = (char*)d_ws + off;
        off += (bytes + 255) & ~(size_t)255;
        return p;
    };
    __bf16* wqkv  = (__bf16*)alloc((size_t)1536 * 512 * 2);
    __bf16* wo    = (__bf16*)alloc((size_t)512 * 512 * 2);
    __bf16* wfc1p = (__bf16*)alloc((size_t)NPACK * 512 * 2);
    __bf16* wfc2p = (__bf16*)alloc((size_t)512 * HC * 2);
    __bf16* xn    = (__bf16*)alloc((size_t)ROWS * Dmod * 2);
    __bf16* xn2   = (__bf16*)alloc((size_t)ROWS * Dmod * 2);
    __bf16* qkb   = (__bf16*)alloc((size_t)ROWS * 1024 * 2);
    __bf16* vtg   = (__bf16*)alloc((size_t)Bdim * Hn * DHd * Nseq * 2);
    __bf16* ctxb  = (__bf16*)alloc((size_t)ROWS * Dmod * 2);
    float*  x1    = (float*)alloc((size_t)ROWS * Dmod * 4);
    __bf16* hcomb = (__bf16*)alloc((size_t)ROWS * HC * 2);
    __bf16* opb   = (__bf16*)alloc((size_t)NSPLIT * ROWS * Dmod * 2);
    float*  lpb   = (float*)alloc((size_t)NSPLIT * Bdim * Hn * Nseq * 4);

    convert_ln<<<CONV_BLOCKS + ROWS, 256, 0, stream>>>(
        q_w, k_w, v_w, o_w, fc1_w, fc2_w, wqkv, wo, wfc1p, wfc2p,
        x, ln1_w, ln1_b, xn);

    qkv_gemm128<<<dim3(ROWS / 128, 12), 256, 0, stream>>>(xn, wqkv, q_b, k_b, v_b, qkb, vtg);

    attn_kernel<<<dim3(Nseq / 64, Hn, Bdim * NSPLIT), 256, 0, stream>>>(
        qkb, vtg, coords, opb, lpb, Nseq / 64 / NSPLIT);
    merge_kernel<<<(ROWS * 128 + 255) / 256, 256, 0, stream>>>(opb, lpb, ctxb);

    gemm_res<<<dim3(ROWS / 64, Dmod / 64), 256, 0, stream>>>(
        ctxb, Dmod, wo, Dmod, o_b, Dmod, x1, Dmod, x, gamma1);

    ln_kernel<<<ROWS, 256, 0, stream>>>(x1, ln2_w, ln2_b, xn2);

    fc1_gemm128<<<dim3(ROWS / 128, NPACK / 128), 256, 0, stream>>>(xn2, wfc1p, fc1_b, hcomb);

    gemm_res<<<dim3(ROWS / 64, Dmod / 64), 256, 0, stream>>>(
        hcomb, HC, wfc2p, HC, fc2_b, HC, (float*)d_out, Dmod, x1, gamma2);
}